// Round 1
// baseline (120865.198 us; speedup 1.0000x reference)
//
#include <hip/hip_runtime.h>

// Problem constants (match reference)
constexpr int Sx = 512;   // source sequence length
constexpr int Nb = 64;    // batch
constexpr int Iw = 256;   // input/feature dim
constexpr int Hd = 1024;  // hidden dim
constexpr int G4 = 4096;  // 4*H (gates i,f,g,o stacked)
constexpr int Td = 128;   // target length

#define DEVFN __device__ __forceinline__

DEVFN float sigmoidf_(float x) { return 1.0f / (1.0f + __expf(-x)); }
DEVFN float tanhf_(float x) {
  const float t = __expf(-2.0f * fabsf(x));
  const float r = (1.0f - t) / (1.0f + t);
  return copysignf(r, x);
}

// ---------------------------------------------------------------------------
// Fused LSTM step: gates = (bias | pre) + xin@W_ih^T + hin@W_hh^T
// grid 256 blocks x 256 threads. Block covers j-tile of 4 (x 4 gates), all n.
// Thread: n = tid>>2 (0..63), jj = tid&3, j = blockIdx*4+jj; 4 accumulators.
// Inputs staged in LDS [64][260] (pad 260: float4-aligned, free 2-way banks).
// ---------------------------------------------------------------------------
__global__ __launch_bounds__(256) void step_kernel(
    const float* __restrict__ xin,   // N x Iw or null
    const float* __restrict__ W_ih,  // G4 x Iw
    const float* __restrict__ hin,   // N x Hd
    const float* __restrict__ W_hh,  // G4 x Hd
    const float* __restrict__ bias,  // G4 or null
    const float* __restrict__ pre,   // N x G4 or null
    float* __restrict__ cst,         // N x Hd (in/out, thread-exclusive)
    float* __restrict__ hout)        // N x Hd
{
  __shared__ float lds[64 * 260];
  const int tid = threadIdx.x;
  const int n = tid >> 2;
  const int jj = tid & 3;
  const int j = blockIdx.x * 4 + jj;

  float a0, a1, a2, a3;
  if (bias) {
    a0 = bias[j]; a1 = bias[Hd + j]; a2 = bias[2 * Hd + j]; a3 = bias[3 * Hd + j];
  } else {
    const float* p = pre + (size_t)n * G4;
    a0 = p[j]; a1 = p[Hd + j]; a2 = p[2 * Hd + j]; a3 = p[3 * Hd + j];
  }

  for (int phase = (xin ? 0 : 1); phase < 2; ++phase) {
    const float* src = (phase == 0) ? xin : hin;
    const float* W   = (phase == 0) ? W_ih : W_hh;
    const int Kw     = (phase == 0) ? Iw : Hd;
    const int nch    = (phase == 0) ? 1 : 4;
    for (int ch = 0; ch < nch; ++ch) {
      const int k0 = ch * 256;
      __syncthreads();
      // stage src[:, k0..k0+256) -> lds  (coalesced float4 global reads)
      for (int idx = tid; idx < 64 * 64; idx += 256) {
        const int nn = idx >> 6, kk = idx & 63;
        *(float4*)(lds + nn * 260 + kk * 4) =
            *(const float4*)(src + (size_t)nn * Kw + k0 + kk * 4);
      }
      __syncthreads();
      const float4* __restrict__ w0 = (const float4*)(W + (size_t)(j) * Kw + k0);
      const float4* __restrict__ w1 = (const float4*)(W + (size_t)(Hd + j) * Kw + k0);
      const float4* __restrict__ w2 = (const float4*)(W + (size_t)(2 * Hd + j) * Kw + k0);
      const float4* __restrict__ w3 = (const float4*)(W + (size_t)(3 * Hd + j) * Kw + k0);
      const float4* __restrict__ xr = (const float4*)(lds + n * 260);
      #pragma unroll 8
      for (int k4 = 0; k4 < 64; ++k4) {
        const float4 xv = xr[k4];
        float4 w;
        w = w0[k4];
        a0 = fmaf(xv.x, w.x, a0); a0 = fmaf(xv.y, w.y, a0);
        a0 = fmaf(xv.z, w.z, a0); a0 = fmaf(xv.w, w.w, a0);
        w = w1[k4];
        a1 = fmaf(xv.x, w.x, a1); a1 = fmaf(xv.y, w.y, a1);
        a1 = fmaf(xv.z, w.z, a1); a1 = fmaf(xv.w, w.w, a1);
        w = w2[k4];
        a2 = fmaf(xv.x, w.x, a2); a2 = fmaf(xv.y, w.y, a2);
        a2 = fmaf(xv.z, w.z, a2); a2 = fmaf(xv.w, w.w, a2);
        w = w3[k4];
        a3 = fmaf(xv.x, w.x, a3); a3 = fmaf(xv.y, w.y, a3);
        a3 = fmaf(xv.z, w.z, a3); a3 = fmaf(xv.w, w.w, a3);
      }
    }
  }

  const float ig = sigmoidf_(a0);
  const float fg = sigmoidf_(a1);
  const float gg = tanhf_(a2);
  const float og = sigmoidf_(a3);
  const int o = n * Hd + j;
  const float cn = fg * cst[o] + ig * gg;
  cst[o] = cn;
  hout[o] = og * tanhf_(cn);
}

// ---------------------------------------------------------------------------
// pre2[sn][i] = b2[i] + sum_h out_e[sn][h] * W2[i][h]
// grid 2048 x 256; block: 16 sn rows (staged in LDS), thread = i.
// ---------------------------------------------------------------------------
__global__ __launch_bounds__(256) void pre2_kernel(
    const float* __restrict__ oute, const float* __restrict__ W2,
    const float* __restrict__ b2, float* __restrict__ pre2)
{
  __shared__ float hl[16 * 1024];
  const int tid = threadIdx.x;
  const int sn0 = blockIdx.x * 16;
  {
    const float4* src = (const float4*)(oute + (size_t)sn0 * Hd);
    float4* dst = (float4*)hl;
    for (int idx = tid; idx < 4096; idx += 256) dst[idx] = src[idx];
  }
  __syncthreads();
  const int i = tid;
  const float4* __restrict__ w = (const float4*)(W2 + (size_t)i * Hd);
  float acc[16];
  #pragma unroll
  for (int ss = 0; ss < 16; ++ss) acc[ss] = 0.0f;
  #pragma unroll 2
  for (int k4 = 0; k4 < 256; ++k4) {
    const float4 wv = w[k4];
    #pragma unroll
    for (int ss = 0; ss < 16; ++ss) {
      const float4 hv = *(const float4*)(hl + ss * 1024 + k4 * 4);
      acc[ss] = fmaf(wv.x, hv.x, acc[ss]); acc[ss] = fmaf(wv.y, hv.y, acc[ss]);
      acc[ss] = fmaf(wv.z, hv.z, acc[ss]); acc[ss] = fmaf(wv.w, hv.w, acc[ss]);
    }
  }
  const float bb = b2[i];
  #pragma unroll
  for (int ss = 0; ss < 16; ++ss)
    pre2[(size_t)(sn0 + ss) * Iw + i] = acc[ss] + bb;
}

// ---------------------------------------------------------------------------
// Per-decoder-step precompute:
//   blocks 0..255 : pre_d[n][g] = bd[g] + sum_k inp[n][k] * Wd_ih[g][k]
//   blocks 256..271: q[n][i]    = b1[i] + sum_h hprev[n][h] * W1[i][h]
// ---------------------------------------------------------------------------
__global__ __launch_bounds__(256) void dec_pre_kernel(
    const float* __restrict__ hprev, const float* __restrict__ W1,
    const float* __restrict__ b1, float* __restrict__ q,
    const float* __restrict__ inp, const float* __restrict__ Wd_ih,
    const float* __restrict__ bd, float* __restrict__ pre_d)
{
  __shared__ float lds[64 * 260];
  const int tid = threadIdx.x;
  if (blockIdx.x < 256) {
    const int g0 = blockIdx.x * 16;
    for (int idx = tid; idx < 4096; idx += 256) {
      const int nn = idx >> 6, kk = idx & 63;
      *(float4*)(lds + nn * 260 + kk * 4) =
          *(const float4*)(inp + (size_t)nn * Iw + kk * 4);
    }
    __syncthreads();
    const int gg = tid >> 4, nn0 = tid & 15;
    const int g = g0 + gg;
    const float4* __restrict__ w = (const float4*)(Wd_ih + (size_t)g * Iw);
    float acc[4] = {0.f, 0.f, 0.f, 0.f};
    #pragma unroll 4
    for (int k4 = 0; k4 < 64; ++k4) {
      const float4 wv = w[k4];
      #pragma unroll
      for (int m = 0; m < 4; ++m) {
        const float4 xv = *(const float4*)(lds + (nn0 + m * 16) * 260 + k4 * 4);
        acc[m] = fmaf(wv.x, xv.x, acc[m]); acc[m] = fmaf(wv.y, xv.y, acc[m]);
        acc[m] = fmaf(wv.z, xv.z, acc[m]); acc[m] = fmaf(wv.w, xv.w, acc[m]);
      }
    }
    const float bv = bd[g];
    #pragma unroll
    for (int m = 0; m < 4; ++m)
      pre_d[(size_t)(nn0 + m * 16) * G4 + g] = acc[m] + bv;
  } else {
    const int n0 = (blockIdx.x - 256) * 4;
    for (int idx = tid; idx < 1024; idx += 256)
      ((float4*)lds)[idx] = ((const float4*)(hprev + (size_t)n0 * Hd))[idx];
    __syncthreads();
    const int i = tid;
    const float4* __restrict__ w = (const float4*)(W1 + (size_t)i * Hd);
    float acc[4] = {0.f, 0.f, 0.f, 0.f};
    #pragma unroll 2
    for (int k4 = 0; k4 < 256; ++k4) {
      const float4 wv = w[k4];
      #pragma unroll
      for (int m = 0; m < 4; ++m) {
        const float4 hv = *(const float4*)(lds + m * 1024 + k4 * 4);
        acc[m] = fmaf(wv.x, hv.x, acc[m]); acc[m] = fmaf(wv.y, hv.y, acc[m]);
        acc[m] = fmaf(wv.z, hv.z, acc[m]); acc[m] = fmaf(wv.w, hv.w, acc[m]);
      }
    }
    const float bv = b1[i];
    #pragma unroll
    for (int m = 0; m < 4; ++m)
      q[(size_t)(n0 + m) * Iw + i] = acc[m] + bv;
  }
}

// ---------------------------------------------------------------------------
// scores[n][s] = b3 + sum_i w3[i] * tanh(pre2[s][n][i] + q[n][i])
// one wave per (s,n); grid 8192 x 256 (4 waves/block).
// ---------------------------------------------------------------------------
__global__ __launch_bounds__(256) void scores_kernel(
    const float* __restrict__ pre2, const float* __restrict__ q,
    const float* __restrict__ w3, const float* __restrict__ b3,
    float* __restrict__ sc)
{
  const int wid = blockIdx.x * 4 + (threadIdx.x >> 6);
  const int lane = threadIdx.x & 63;
  const int s = wid >> 6, n = wid & 63;
  const float4 p  = *(const float4*)(pre2 + (size_t)(s * Nb + n) * Iw + lane * 4);
  const float4 qv = *(const float4*)(q + (size_t)n * Iw + lane * 4);
  const float4 wv = *(const float4*)(w3 + lane * 4);
  float acc = tanhf_(p.x + qv.x) * wv.x + tanhf_(p.y + qv.y) * wv.y +
              tanhf_(p.z + qv.z) * wv.z + tanhf_(p.w + qv.w) * wv.w;
  #pragma unroll
  for (int off = 32; off; off >>= 1) acc += __shfl_xor(acc, off);
  if (lane == 0) sc[n * Sx + s] = acc + b3[0];
}

// ---------------------------------------------------------------------------
// Softmax over s (per n) + ctx[n][h] = sum_s alpha[s] * out_e[s][n][h]
// grid 256 (n x 4 h-tiles) x 256 threads.
// ---------------------------------------------------------------------------
__global__ __launch_bounds__(256) void ctx_kernel(
    const float* __restrict__ sc, const float* __restrict__ oute,
    float* __restrict__ ctx)
{
  __shared__ float sal[512];
  __shared__ float red[256];
  const int tid = threadIdx.x;
  const int n = blockIdx.x >> 2, ht = blockIdx.x & 3;
  const float s0 = sc[n * Sx + tid];
  const float s1 = sc[n * Sx + 256 + tid];
  red[tid] = fmaxf(s0, s1);
  __syncthreads();
  for (int w = 128; w; w >>= 1) {
    if (tid < w) red[tid] = fmaxf(red[tid], red[tid + w]);
    __syncthreads();
  }
  const float mx = red[0];
  __syncthreads();
  const float e0 = __expf(s0 - mx), e1 = __expf(s1 - mx);
  sal[tid] = e0; sal[tid + 256] = e1;
  red[tid] = e0 + e1;
  __syncthreads();
  for (int w = 128; w; w >>= 1) {
    if (tid < w) red[tid] += red[tid + w];
    __syncthreads();
  }
  const float inv = 1.0f / red[0];
  const int h = ht * 256 + tid;
  const float* __restrict__ base = oute + (size_t)n * Hd + h;
  float A0 = 0.f, A1 = 0.f, A2 = 0.f, A3 = 0.f;
  #pragma unroll 2
  for (int s = 0; s < Sx; s += 4) {
    A0 = fmaf(sal[s],     base[(size_t)(s)     * (Nb * Hd)], A0);
    A1 = fmaf(sal[s + 1], base[(size_t)(s + 1) * (Nb * Hd)], A1);
    A2 = fmaf(sal[s + 2], base[(size_t)(s + 2) * (Nb * Hd)], A2);
    A3 = fmaf(sal[s + 3], base[(size_t)(s + 3) * (Nb * Hd)], A3);
  }
  ctx[(size_t)n * Hd + h] = (A0 + A1 + A2 + A3) * inv;
}

// ---------------------------------------------------------------------------
// out[n][i] = bias[i] + sum_h hin[n][h] * W[i][h]   (grid 16 x 256)
// ---------------------------------------------------------------------------
__global__ __launch_bounds__(256) void outlin_kernel(
    const float* __restrict__ hin, const float* __restrict__ W,
    const float* __restrict__ bias, float* __restrict__ out)
{
  __shared__ float hl[4 * 1024];
  const int tid = threadIdx.x;
  const int n0 = blockIdx.x * 4;
  for (int idx = tid; idx < 1024; idx += 256)
    ((float4*)hl)[idx] = ((const float4*)(hin + (size_t)n0 * Hd))[idx];
  __syncthreads();
  const int i = tid;
  const float4* __restrict__ w = (const float4*)(W + (size_t)i * Hd);
  float acc[4] = {0.f, 0.f, 0.f, 0.f};
  #pragma unroll 2
  for (int k4 = 0; k4 < 256; ++k4) {
    const float4 wv = w[k4];
    #pragma unroll
    for (int m = 0; m < 4; ++m) {
      const float4 hv = *(const float4*)(hl + m * 1024 + k4 * 4);
      acc[m] = fmaf(wv.x, hv.x, acc[m]); acc[m] = fmaf(wv.y, hv.y, acc[m]);
      acc[m] = fmaf(wv.z, hv.z, acc[m]); acc[m] = fmaf(wv.w, hv.w, acc[m]);
    }
  }
  const float bv = bias[i];
  #pragma unroll
  for (int m = 0; m < 4; ++m)
    out[(size_t)(n0 + m) * Iw + i] = acc[m] + bv;
}

// ---------------------------------------------------------------------------
extern "C" void kernel_launch(void* const* d_in, const int* in_sizes, int n_in,
                              void* d_out, int out_size, void* d_ws, size_t ws_size,
                              hipStream_t stream) {
  (void)in_sizes; (void)n_in; (void)out_size; (void)ws_size;
  const float* x     = (const float*)d_in[0];
  // d_in[1] = target_len (constant 128) — ignored
  const float* We_ih = (const float*)d_in[2];
  const float* We_hh = (const float*)d_in[3];
  const float* be    = (const float*)d_in[4];
  const float* Wd_ih = (const float*)d_in[5];
  const float* Wd_hh = (const float*)d_in[6];
  const float* bd    = (const float*)d_in[7];
  const float* W1    = (const float*)d_in[8];
  const float* b1    = (const float*)d_in[9];
  const float* W2    = (const float*)d_in[10];
  const float* b2    = (const float*)d_in[11];
  const float* w3    = (const float*)d_in[12];
  const float* b3    = (const float*)d_in[13];
  const float* Wl    = (const float*)d_in[14];
  const float* bl    = (const float*)d_in[15];
  float* out = (float*)d_out;

  // Workspace layout (floats): ~162 MiB total
  float* ws    = (float*)d_ws;
  float* out_e = ws;                                   // S*N*H
  float* pre2  = out_e + (size_t)Sx * Nb * Hd;         // S*N*I
  float* c_buf = pre2 + (size_t)Sx * Nb * Iw;          // N*H
  float* zero_h = c_buf + (size_t)Nb * Hd;             // N*H
  float* h_d   = zero_h + (size_t)Nb * Hd;             // N*H
  float* ctxb  = h_d + (size_t)Nb * Hd;                // N*H
  float* qb    = ctxb + (size_t)Nb * Hd;               // N*I
  float* pre_d = qb + (size_t)Nb * Iw;                 // N*4H
  float* scb   = pre_d + (size_t)Nb * G4;              // N*S

  hipMemsetAsync(zero_h, 0, (size_t)Nb * Hd * sizeof(float), stream);
  hipMemsetAsync(c_buf, 0, (size_t)Nb * Hd * sizeof(float), stream);

  // ---- Encoder: 512 sequential fused LSTM steps ----
  for (int t = 0; t < Sx; ++t) {
    const float* hprev = t ? (out_e + (size_t)(t - 1) * Nb * Hd) : zero_h;
    step_kernel<<<256, 256, 0, stream>>>(
        x + (size_t)t * Nb * Iw, We_ih, hprev, We_hh, be, nullptr,
        c_buf, out_e + (size_t)t * Nb * Hd);
  }

  // ---- pre2 = linear2(out_e) (shared across decode steps) ----
  pre2_kernel<<<2048, 256, 0, stream>>>(out_e, W2, b2, pre2);

  // ---- Decoder: 128 sequential steps with Bahdanau attention ----
  for (int t = 0; t < Td; ++t) {
    const float* hprev = t ? h_d : (out_e + (size_t)(Sx - 1) * Nb * Hd);
    const float* inp   = t ? (out + (size_t)(t - 1) * Nb * Iw)
                           : (x + (size_t)(Sx - 1) * Nb * Iw);
    dec_pre_kernel<<<272, 256, 0, stream>>>(hprev, W1, b1, qb,
                                            inp, Wd_ih, bd, pre_d);
    scores_kernel<<<8192, 256, 0, stream>>>(pre2, qb, w3, b3, scb);
    ctx_kernel<<<256, 256, 0, stream>>>(scb, out_e, ctxb);
    step_kernel<<<256, 256, 0, stream>>>(nullptr, nullptr, ctxb, Wd_hh,
                                         nullptr, pre_d, c_buf, h_d);
    outlin_kernel<<<16, 256, 0, stream>>>(h_d, Wl, bl,
                                          out + (size_t)t * Nb * Iw);
  }
}

// Round 2
// 106660.938 us; speedup vs baseline: 1.1332x; 1.1332x over previous
//
#include <hip/hip_runtime.h>

// Problem constants (match reference)
constexpr int Sx = 512;   // source sequence length
constexpr int Nb = 64;    // batch
constexpr int Iw = 256;   // input/feature dim
constexpr int Hd = 1024;  // hidden dim
constexpr int G4 = 4096;  // 4*H (gates i,f,g,o stacked)
constexpr int Td = 128;   // target length
constexpr int NH = Nb * Hd;   // 65536
constexpr int NG = Nb * G4;   // 262144

#define DEVFN __device__ __forceinline__

DEVFN float sigmoidf_(float x) { return 1.0f / (1.0f + __expf(-x)); }
DEVFN float tanhf_(float x) {
  const float t = __expf(-2.0f * fabsf(x));
  const float r = (1.0f - t) / (1.0f + t);
  return copysignf(r, x);
}

// ---------------------------------------------------------------------------
// gemm4: partial gate pre-activations for one LSTM step.
//   part[ks][n][g*1024+j] = sum_{k in Kchunk(ks)} hid[n][k] * Whh[g*1024+j][k]
//                         (+ x-slice contribution if xin != null)
// grid = 512 blocks (128 j-groups x 4 k-splits) x 512 threads (4 waves/SIMD).
// thread: n = tid>>3 (0..63), jj = tid&7; j = jg*8+jj; acc[4 gates].
// hid = hin (+ hin2 if non-null, for split-context sum).
// LDS [64][260] fp32 (pad 260: float4-aligned, conflict-free b128 reads).
// ---------------------------------------------------------------------------
__global__ __launch_bounds__(512, 4) void gemm4_kernel(
    const float* __restrict__ hin,   // N x Hd
    const float* __restrict__ hin2,  // N x Hd or null (added to hin)
    const float* __restrict__ Whh,   // G4 x Hd
    const float* __restrict__ xin,   // N x Iw or null
    const float* __restrict__ Wih,   // G4 x Iw (used when xin != null)
    float* __restrict__ part)        // 4 x N x G4
{
  __shared__ float lds[64 * 260];
  const int tid = threadIdx.x;
  const int jg = blockIdx.x >> 2;
  const int ks = blockIdx.x & 3;
  const int n  = tid >> 3;
  const int jj = tid & 7;
  const int j  = jg * 8 + jj;

  float a0 = 0.f, a1 = 0.f, a2 = 0.f, a3 = 0.f;

  // ---- Phase H: hidden @ Whh^T over K-chunk [ks*256, ks*256+256) ----
  {
    for (int idx = tid; idx < 4096; idx += 512) {
      const int nn = idx >> 6, kk = idx & 63;
      float4 v = *(const float4*)(hin + (size_t)nn * Hd + ks * 256 + kk * 4);
      if (hin2) {
        const float4 u = *(const float4*)(hin2 + (size_t)nn * Hd + ks * 256 + kk * 4);
        v.x += u.x; v.y += u.y; v.z += u.z; v.w += u.w;
      }
      *(float4*)(lds + nn * 260 + kk * 4) = v;
    }
    __syncthreads();
    const float4* __restrict__ w0 = (const float4*)(Whh + (size_t)j * Hd + ks * 256);
    const float4* __restrict__ w1 = (const float4*)(Whh + (size_t)(Hd + j) * Hd + ks * 256);
    const float4* __restrict__ w2 = (const float4*)(Whh + (size_t)(2 * Hd + j) * Hd + ks * 256);
    const float4* __restrict__ w3 = (const float4*)(Whh + (size_t)(3 * Hd + j) * Hd + ks * 256);
    const float4* __restrict__ xr = (const float4*)(lds + n * 260);
    #pragma unroll 2
    for (int k4 = 0; k4 < 64; ++k4) {
      const float4 xv = xr[k4];
      float4 w;
      w = w0[k4];
      a0 = fmaf(xv.x, w.x, a0); a0 = fmaf(xv.y, w.y, a0);
      a0 = fmaf(xv.z, w.z, a0); a0 = fmaf(xv.w, w.w, a0);
      w = w1[k4];
      a1 = fmaf(xv.x, w.x, a1); a1 = fmaf(xv.y, w.y, a1);
      a1 = fmaf(xv.z, w.z, a1); a1 = fmaf(xv.w, w.w, a1);
      w = w2[k4];
      a2 = fmaf(xv.x, w.x, a2); a2 = fmaf(xv.y, w.y, a2);
      a2 = fmaf(xv.z, w.z, a2); a2 = fmaf(xv.w, w.w, a2);
      w = w3[k4];
      a3 = fmaf(xv.x, w.x, a3); a3 = fmaf(xv.y, w.y, a3);
      a3 = fmaf(xv.z, w.z, a3); a3 = fmaf(xv.w, w.w, a3);
    }
  }

  // ---- Phase X: x @ Wih^T over K-chunk [ks*64, ks*64+64) ----
  if (xin) {
    __syncthreads();  // protect lds reuse
    for (int idx = tid; idx < 1024; idx += 512) {
      const int nn = idx >> 4, kk = idx & 15;
      *(float4*)(lds + nn * 68 + kk * 4) =
          *(const float4*)(xin + (size_t)nn * Iw + ks * 64 + kk * 4);
    }
    __syncthreads();
    const float4* __restrict__ w0 = (const float4*)(Wih + (size_t)j * Iw + ks * 64);
    const float4* __restrict__ w1 = (const float4*)(Wih + (size_t)(Hd + j) * Iw + ks * 64);
    const float4* __restrict__ w2 = (const float4*)(Wih + (size_t)(2 * Hd + j) * Iw + ks * 64);
    const float4* __restrict__ w3 = (const float4*)(Wih + (size_t)(3 * Hd + j) * Iw + ks * 64);
    const float4* __restrict__ xr = (const float4*)(lds + n * 68);
    #pragma unroll 2
    for (int k4 = 0; k4 < 16; ++k4) {
      const float4 xv = xr[k4];
      float4 w;
      w = w0[k4];
      a0 = fmaf(xv.x, w.x, a0); a0 = fmaf(xv.y, w.y, a0);
      a0 = fmaf(xv.z, w.z, a0); a0 = fmaf(xv.w, w.w, a0);
      w = w1[k4];
      a1 = fmaf(xv.x, w.x, a1); a1 = fmaf(xv.y, w.y, a1);
      a1 = fmaf(xv.z, w.z, a1); a1 = fmaf(xv.w, w.w, a1);
      w = w2[k4];
      a2 = fmaf(xv.x, w.x, a2); a2 = fmaf(xv.y, w.y, a2);
      a2 = fmaf(xv.z, w.z, a2); a2 = fmaf(xv.w, w.w, a2);
      w = w3[k4];
      a3 = fmaf(xv.x, w.x, a3); a3 = fmaf(xv.y, w.y, a3);
      a3 = fmaf(xv.z, w.z, a3); a3 = fmaf(xv.w, w.w, a3);
    }
  }

  float* pp = part + ((size_t)ks * Nb + n) * G4 + j;
  pp[0] = a0; pp[Hd] = a1; pp[2 * Hd] = a2; pp[3 * Hd] = a3;
}

// ---------------------------------------------------------------------------
// gates: reduce 4 K-split partials + (bias | pre), apply LSTM nonlinearity.
// grid 256 x 256; thread -> output element (n, j).
// ---------------------------------------------------------------------------
__global__ __launch_bounds__(256) void gates_kernel(
    const float* __restrict__ pre,   // N x G4 or null
    const float* __restrict__ bias,  // G4 or null
    const float* __restrict__ part,  // 4 x N x G4
    float* __restrict__ cst,         // N x Hd (in/out)
    float* __restrict__ hout)        // N x Hd
{
  const int o = blockIdx.x * 256 + threadIdx.x;  // 0..65535
  const int n = o >> 10, j = o & 1023;
  const size_t base = (size_t)n * G4 + j;
  float v0, v1, v2, v3;
  if (bias) {
    v0 = bias[j]; v1 = bias[Hd + j]; v2 = bias[2 * Hd + j]; v3 = bias[3 * Hd + j];
  } else {
    v0 = pre[base]; v1 = pre[base + Hd]; v2 = pre[base + 2 * Hd]; v3 = pre[base + 3 * Hd];
  }
  #pragma unroll
  for (int ks = 0; ks < 4; ++ks) {
    const float* p = part + (size_t)ks * NG + base;
    v0 += p[0]; v1 += p[Hd]; v2 += p[2 * Hd]; v3 += p[3 * Hd];
  }
  const float ig = sigmoidf_(v0);
  const float fg = sigmoidf_(v1);
  const float gg = tanhf_(v2);
  const float og = sigmoidf_(v3);
  const int oo = n * Hd + j;
  const float cn = fg * cst[oo] + ig * gg;
  cst[oo] = cn;
  hout[oo] = og * tanhf_(cn);
}

// ---------------------------------------------------------------------------
// pre2[sn][i] = b2[i] + sum_h out_e[sn][h] * W2[i][h]   (grid 2048 x 256)
// ---------------------------------------------------------------------------
__global__ __launch_bounds__(256) void pre2_kernel(
    const float* __restrict__ oute, const float* __restrict__ W2,
    const float* __restrict__ b2, float* __restrict__ pre2)
{
  __shared__ float hl[16 * 1024];
  const int tid = threadIdx.x;
  const int sn0 = blockIdx.x * 16;
  {
    const float4* src = (const float4*)(oute + (size_t)sn0 * Hd);
    float4* dst = (float4*)hl;
    for (int idx = tid; idx < 4096; idx += 256) dst[idx] = src[idx];
  }
  __syncthreads();
  const int i = tid;
  const float4* __restrict__ w = (const float4*)(W2 + (size_t)i * Hd);
  float acc[16];
  #pragma unroll
  for (int ss = 0; ss < 16; ++ss) acc[ss] = 0.0f;
  #pragma unroll 2
  for (int k4 = 0; k4 < 256; ++k4) {
    const float4 wv = w[k4];
    #pragma unroll
    for (int ss = 0; ss < 16; ++ss) {
      const float4 hv = *(const float4*)(hl + ss * 1024 + k4 * 4);
      acc[ss] = fmaf(wv.x, hv.x, acc[ss]); acc[ss] = fmaf(wv.y, hv.y, acc[ss]);
      acc[ss] = fmaf(wv.z, hv.z, acc[ss]); acc[ss] = fmaf(wv.w, hv.w, acc[ss]);
    }
  }
  const float bb = b2[i];
  #pragma unroll
  for (int ss = 0; ss < 16; ++ss)
    pre2[(size_t)(sn0 + ss) * Iw + i] = acc[ss] + bb;
}

// ---------------------------------------------------------------------------
// Per-decoder-step precompute:
//   blocks 0..255 : pre_d[n][g] = bd[g] + sum_k inp[n][k] * Wd_ih[g][k]
//   blocks 256..271: q[n][i]    = b1[i] + sum_h hprev[n][h] * W1[i][h]
// ---------------------------------------------------------------------------
__global__ __launch_bounds__(256) void dec_pre_kernel(
    const float* __restrict__ hprev, const float* __restrict__ W1,
    const float* __restrict__ b1, float* __restrict__ q,
    const float* __restrict__ inp, const float* __restrict__ Wd_ih,
    const float* __restrict__ bd, float* __restrict__ pre_d)
{
  __shared__ float lds[64 * 260];
  const int tid = threadIdx.x;
  if (blockIdx.x < 256) {
    const int g0 = blockIdx.x * 16;
    for (int idx = tid; idx < 4096; idx += 256) {
      const int nn = idx >> 6, kk = idx & 63;
      *(float4*)(lds + nn * 260 + kk * 4) =
          *(const float4*)(inp + (size_t)nn * Iw + kk * 4);
    }
    __syncthreads();
    const int gg = tid >> 4, nn0 = tid & 15;
    const int g = g0 + gg;
    const float4* __restrict__ w = (const float4*)(Wd_ih + (size_t)g * Iw);
    float acc[4] = {0.f, 0.f, 0.f, 0.f};
    #pragma unroll 4
    for (int k4 = 0; k4 < 64; ++k4) {
      const float4 wv = w[k4];
      #pragma unroll
      for (int m = 0; m < 4; ++m) {
        const float4 xv = *(const float4*)(lds + (nn0 + m * 16) * 260 + k4 * 4);
        acc[m] = fmaf(wv.x, xv.x, acc[m]); acc[m] = fmaf(wv.y, xv.y, acc[m]);
        acc[m] = fmaf(wv.z, xv.z, acc[m]); acc[m] = fmaf(wv.w, xv.w, acc[m]);
      }
    }
    const float bv = bd[g];
    #pragma unroll
    for (int m = 0; m < 4; ++m)
      pre_d[(size_t)(nn0 + m * 16) * G4 + g] = acc[m] + bv;
  } else {
    const int n0 = (blockIdx.x - 256) * 4;
    for (int idx = tid; idx < 1024; idx += 256)
      ((float4*)lds)[idx] = ((const float4*)(hprev + (size_t)n0 * Hd))[idx];
    __syncthreads();
    const int i = tid;
    const float4* __restrict__ w = (const float4*)(W1 + (size_t)i * Hd);
    float acc[4] = {0.f, 0.f, 0.f, 0.f};
    #pragma unroll 2
    for (int k4 = 0; k4 < 256; ++k4) {
      const float4 wv = w[k4];
      #pragma unroll
      for (int m = 0; m < 4; ++m) {
        const float4 hv = *(const float4*)(lds + m * 1024 + k4 * 4);
        acc[m] = fmaf(wv.x, hv.x, acc[m]); acc[m] = fmaf(wv.y, hv.y, acc[m]);
        acc[m] = fmaf(wv.z, hv.z, acc[m]); acc[m] = fmaf(wv.w, hv.w, acc[m]);
      }
    }
    const float bv = b1[i];
    #pragma unroll
    for (int m = 0; m < 4; ++m)
      q[(size_t)(n0 + m) * Iw + i] = acc[m] + bv;
  }
}

// ---------------------------------------------------------------------------
// scores[n][s] = b3 + sum_i w3[i] * tanh(pre2[s][n][i] + q[n][i])
// one wave per (s,n); grid 8192 x 256 (4 waves/block).
// ---------------------------------------------------------------------------
__global__ __launch_bounds__(256) void scores_kernel(
    const float* __restrict__ pre2, const float* __restrict__ q,
    const float* __restrict__ w3, const float* __restrict__ b3,
    float* __restrict__ sc)
{
  const int wid = blockIdx.x * 4 + (threadIdx.x >> 6);
  const int lane = threadIdx.x & 63;
  const int s = wid >> 6, n = wid & 63;
  const float4 p  = *(const float4*)(pre2 + (size_t)(s * Nb + n) * Iw + lane * 4);
  const float4 qv = *(const float4*)(q + (size_t)n * Iw + lane * 4);
  const float4 wv = *(const float4*)(w3 + lane * 4);
  float acc = tanhf_(p.x + qv.x) * wv.x + tanhf_(p.y + qv.y) * wv.y +
              tanhf_(p.z + qv.z) * wv.z + tanhf_(p.w + qv.w) * wv.w;
  #pragma unroll
  for (int off = 32; off; off >>= 1) acc += __shfl_xor(acc, off);
  if (lane == 0) sc[n * Sx + s] = acc + b3[0];
}

// ---------------------------------------------------------------------------
// Softmax over s (per n) + half-range weighted sum of out_e.
// grid 512 (n x 4 h-tiles x 2 s-halves) x 256 threads.
// ctxp[sh][n][h] = sum_{s in half sh} alpha[s] * out_e[s][n][h]
// ---------------------------------------------------------------------------
__global__ __launch_bounds__(256) void ctx2_kernel(
    const float* __restrict__ sc, const float* __restrict__ oute,
    float* __restrict__ ctxp)   // 2 x N x Hd
{
  __shared__ float sal[512];
  __shared__ float red[256];
  const int tid = threadIdx.x;
  const int n = blockIdx.x >> 3;
  const int ht = (blockIdx.x >> 1) & 3;
  const int sh = blockIdx.x & 1;
  const float s0 = sc[n * Sx + tid];
  const float s1 = sc[n * Sx + 256 + tid];
  red[tid] = fmaxf(s0, s1);
  __syncthreads();
  for (int w = 128; w; w >>= 1) {
    if (tid < w) red[tid] = fmaxf(red[tid], red[tid + w]);
    __syncthreads();
  }
  const float mx = red[0];
  __syncthreads();
  const float e0 = __expf(s0 - mx), e1 = __expf(s1 - mx);
  sal[tid] = e0; sal[tid + 256] = e1;
  red[tid] = e0 + e1;
  __syncthreads();
  for (int w = 128; w; w >>= 1) {
    if (tid < w) red[tid] += red[tid + w];
    __syncthreads();
  }
  const float inv = 1.0f / red[0];
  const int h = ht * 256 + tid;
  const float* __restrict__ base = oute + (size_t)(sh * 256) * NH + n * Hd + h;
  const float* __restrict__ al = sal + sh * 256;
  float A[8] = {0.f, 0.f, 0.f, 0.f, 0.f, 0.f, 0.f, 0.f};
  for (int s8 = 0; s8 < 256; s8 += 8) {
    #pragma unroll
    for (int u = 0; u < 8; ++u)
      A[u] = fmaf(al[s8 + u], base[(size_t)(s8 + u) * NH], A[u]);
  }
  const float tot = ((A[0] + A[1]) + (A[2] + A[3])) + ((A[4] + A[5]) + (A[6] + A[7]));
  ctxp[(size_t)sh * NH + n * Hd + h] = tot * inv;
}

// ---------------------------------------------------------------------------
// out[n][i] = bias[i] + sum_h hin[n][h] * W[i][h]   (grid 16 x 256)
// ---------------------------------------------------------------------------
__global__ __launch_bounds__(256) void outlin_kernel(
    const float* __restrict__ hin, const float* __restrict__ W,
    const float* __restrict__ bias, float* __restrict__ out)
{
  __shared__ float hl[4 * 1024];
  const int tid = threadIdx.x;
  const int n0 = blockIdx.x * 4;
  for (int idx = tid; idx < 1024; idx += 256)
    ((float4*)hl)[idx] = ((const float4*)(hin + (size_t)n0 * Hd))[idx];
  __syncthreads();
  const int i = tid;
  const float4* __restrict__ w = (const float4*)(W + (size_t)i * Hd);
  float acc[4] = {0.f, 0.f, 0.f, 0.f};
  #pragma unroll 2
  for (int k4 = 0; k4 < 256; ++k4) {
    const float4 wv = w[k4];
    #pragma unroll
    for (int m = 0; m < 4; ++m) {
      const float4 hv = *(const float4*)(hl + m * 1024 + k4 * 4);
      acc[m] = fmaf(wv.x, hv.x, acc[m]); acc[m] = fmaf(wv.y, hv.y, acc[m]);
      acc[m] = fmaf(wv.z, hv.z, acc[m]); acc[m] = fmaf(wv.w, hv.w, acc[m]);
    }
  }
  const float bv = bias[i];
  #pragma unroll
  for (int m = 0; m < 4; ++m)
    out[(size_t)(n0 + m) * Iw + i] = acc[m] + bv;
}

// ---------------------------------------------------------------------------
extern "C" void kernel_launch(void* const* d_in, const int* in_sizes, int n_in,
                              void* d_out, int out_size, void* d_ws, size_t ws_size,
                              hipStream_t stream) {
  (void)in_sizes; (void)n_in; (void)out_size; (void)ws_size;
  const float* x     = (const float*)d_in[0];
  // d_in[1] = target_len (constant 128) — ignored
  const float* We_ih = (const float*)d_in[2];
  const float* We_hh = (const float*)d_in[3];
  const float* be    = (const float*)d_in[4];
  const float* Wd_ih = (const float*)d_in[5];
  const float* Wd_hh = (const float*)d_in[6];
  const float* bd    = (const float*)d_in[7];
  const float* W1    = (const float*)d_in[8];
  const float* b1    = (const float*)d_in[9];
  const float* W2    = (const float*)d_in[10];
  const float* b2    = (const float*)d_in[11];
  const float* w3    = (const float*)d_in[12];
  const float* b3    = (const float*)d_in[13];
  const float* Wl    = (const float*)d_in[14];
  const float* bl    = (const float*)d_in[15];
  float* out = (float*)d_out;

  // Workspace layout (floats): ~175 MiB total
  float* ws    = (float*)d_ws;
  float* out_e = ws;                                   // S*N*H    (128 MB)
  float* pre2  = out_e + (size_t)Sx * NH;              // S*N*I    (32 MB)
  float* part  = pre2 + (size_t)Sx * Nb * Iw;          // 4*N*4H   (4 MB)
  float* c_buf = part + (size_t)4 * NG;                // N*H
  float* zero_h = c_buf + NH;                          // N*H
  float* h_d   = zero_h + NH;                          // N*H
  float* ctxp  = h_d + NH;                             // 2*N*H
  float* qb    = ctxp + 2 * NH;                        // N*I
  float* pre_d = qb + Nb * Iw;                         // N*4H
  float* scb   = pre_d + NG;                           // N*S

  hipMemsetAsync(zero_h, 0, (size_t)NH * sizeof(float), stream);
  hipMemsetAsync(c_buf, 0, (size_t)NH * sizeof(float), stream);

  // ---- Encoder: 512 sequential steps (gemm4 + gates) ----
  for (int t = 0; t < Sx; ++t) {
    const float* hprev = t ? (out_e + (size_t)(t - 1) * NH) : zero_h;
    gemm4_kernel<<<512, 512, 0, stream>>>(
        hprev, nullptr, We_hh, x + (size_t)t * Nb * Iw, We_ih, part);
    gates_kernel<<<256, 256, 0, stream>>>(
        nullptr, be, part, c_buf, out_e + (size_t)t * NH);
  }

  // ---- pre2 = linear2(out_e) (shared across decode steps) ----
  pre2_kernel<<<2048, 256, 0, stream>>>(out_e, W2, b2, pre2);

  // ---- Decoder: 128 sequential steps with Bahdanau attention ----
  for (int t = 0; t < Td; ++t) {
    const float* hprev = t ? h_d : (out_e + (size_t)(Sx - 1) * NH);
    const float* inp   = t ? (out + (size_t)(t - 1) * Nb * Iw)
                           : (x + (size_t)(Sx - 1) * Nb * Iw);
    dec_pre_kernel<<<272, 256, 0, stream>>>(hprev, W1, b1, qb,
                                            inp, Wd_ih, bd, pre_d);
    scores_kernel<<<8192, 256, 0, stream>>>(pre2, qb, w3, b3, scb);
    ctx2_kernel<<<512, 256, 0, stream>>>(scb, out_e, ctxp);
    gemm4_kernel<<<512, 512, 0, stream>>>(
        ctxp, ctxp + NH, Wd_hh, nullptr, nullptr, part);
    gates_kernel<<<256, 256, 0, stream>>>(
        pre_d, nullptr, part, c_buf, h_d);
    outlin_kernel<<<16, 256, 0, stream>>>(h_d, Wl, bl,
                                          out + (size_t)t * Nb * Iw);
  }
}

// Round 4
// 39363.974 us; speedup vs baseline: 3.0705x; 2.7096x over previous
//
#include <hip/hip_runtime.h>

// Problem constants (match reference)
constexpr int Sx = 512;   // source sequence length
constexpr int Nb = 64;    // batch
constexpr int Iw = 256;   // input/feature dim
constexpr int Hd = 1024;  // hidden dim
constexpr int Td = 128;   // target length
constexpr int NH = Nb * Hd;   // 65536
constexpr int NI = Nb * Iw;   // 16384
constexpr int NBLK = 256;
constexpr int NTHR = 512;

#define DEVFN __device__ __forceinline__

DEVFN float sigmoidf_(float x) { return 1.0f / (1.0f + __expf(-x)); }
DEVFN float tanhf_(float x) {
  const float t = __expf(-2.0f * fabsf(x));
  const float r = (1.0f - t) / (1.0f + t);
  return copysignf(r, x);
}

// Device-scope grid barrier (sense via generation counter). cnt/gen zeroed
// by host memset each launch. Writer visibility: __threadfence (device
// release) before arrive; readers: relaxed spin + __threadfence after.
DEVFN void gridbar(int* cnt, int* gen) {
  __syncthreads();
  if (threadIdx.x == 0) {
    __threadfence();
    int g = __hip_atomic_load(gen, __ATOMIC_RELAXED, __HIP_MEMORY_SCOPE_AGENT);
    int a = __hip_atomic_fetch_add(cnt, 1, __ATOMIC_ACQ_REL, __HIP_MEMORY_SCOPE_AGENT);
    if (a == NBLK - 1) {
      __hip_atomic_store(cnt, 0, __ATOMIC_RELAXED, __HIP_MEMORY_SCOPE_AGENT);
      __hip_atomic_fetch_add(gen, 1, __ATOMIC_RELEASE, __HIP_MEMORY_SCOPE_AGENT);
    } else {
      while (__hip_atomic_load(gen, __ATOMIC_RELAXED, __HIP_MEMORY_SCOPE_AGENT) == g)
        __builtin_amdgcn_s_sleep(2);
    }
    __threadfence();
  }
  __syncthreads();
}

// ---------------------------------------------------------------------------
// One LSTM step for this block's 4 j-columns (x 4 gates = 16 weight rows,
// resident in w_lds[16][1280]: k 0..1023 = W_hh, 1024..1279 = W_ih).
// Full-K in-block: gates + c-update + h-write all local. Thread tile:
// (rg,ng,ks) = 4 rows x 4 n x 8-way interleaved k-slices; LDS stage stride
// 258 (8B-aligned rows, conflict-benign banks).
// ---------------------------------------------------------------------------
DEVFN void lstm_tile_step(
    const float* hsrc,               // N x Hd  (h_prev or ctx)
    const float* xsrc,               // N x Iw  (x_t or inp)
    float* hdst,                     // N x Hd
    const float* w_lds, float* stage, float* c_lds, const float* b_lds,
    int j0, int tid)
{
  const int rg = tid >> 7;          // 0..3
  const int ng = (tid >> 3) & 15;   // 0..15
  const int ks = tid & 7;           // 0..7
  float acc[4][4];
  #pragma unroll
  for (int i = 0; i < 4; ++i)
    #pragma unroll
    for (int j = 0; j < 4; ++j) acc[i][j] = 0.f;

  for (int c = 0; c < 5; ++c) {
    __syncthreads();
    const float* src = (c < 4) ? (hsrc + c * 256) : xsrc;
    const int sstr = (c < 4) ? Hd : Iw;
    for (int idx = tid; idx < 4096; idx += NTHR) {
      const int nn = idx >> 6, kf = idx & 63;
      const float4 v = *(const float4*)(src + (size_t)nn * sstr + kf * 4);
      float* d = stage + nn * 258 + kf * 4;
      d[0] = v.x; d[1] = v.y; d[2] = v.z; d[3] = v.w;
    }
    __syncthreads();
    #pragma unroll
    for (int kk = 0; kk < 8; ++kk) {
      const int kf4 = kk * 8 + ks;
      float4 wv[4];
      #pragma unroll
      for (int i = 0; i < 4; ++i)
        wv[i] = *(const float4*)(w_lds + (size_t)(rg * 4 + i) * 1280 + c * 256 + kf4 * 4);
      #pragma unroll
      for (int j = 0; j < 4; ++j) {
        const float* hp = stage + (ng * 4 + j) * 258 + kf4 * 4;
        const float h0 = hp[0], h1 = hp[1], h2 = hp[2], h3 = hp[3];
        #pragma unroll
        for (int i = 0; i < 4; ++i) {
          acc[i][j] = fmaf(wv[i].x, h0, acc[i][j]);
          acc[i][j] = fmaf(wv[i].y, h1, acc[i][j]);
          acc[i][j] = fmaf(wv[i].z, h2, acc[i][j]);
          acc[i][j] = fmaf(wv[i].w, h3, acc[i][j]);
        }
      }
    }
  }
  // reduce the 8 k-slice partials per output, then gates (local j-slice)
  __syncthreads();
  #pragma unroll
  for (int i = 0; i < 4; ++i)
    #pragma unroll
    for (int j = 0; j < 4; ++j)
      stage[((rg * 4 + i) * 64 + (ng * 4 + j)) * 8 + ks] = acc[i][j];
  __syncthreads();
  if (tid < 256) {
    const int n = tid >> 2, jj = tid & 3;
    float v[4];
    #pragma unroll
    for (int g = 0; g < 4; ++g) {
      const int r = g * 4 + jj;
      const float* p = stage + ((size_t)r * 64 + n) * 8;
      v[g] = b_lds[r] + ((p[0] + p[1]) + (p[2] + p[3])) + ((p[4] + p[5]) + (p[6] + p[7]));
    }
    const float ig = sigmoidf_(v[0]);
    const float fg = sigmoidf_(v[1]);
    const float gg = tanhf_(v[2]);
    const float og = sigmoidf_(v[3]);
    const float cn = fg * c_lds[tid] + ig * gg;
    c_lds[tid] = cn;
    hdst[(size_t)n * Hd + j0 + jj] = og * tanhf_(cn);
  }
}

// ---------------------------------------------------------------------------
// Encoder megakernel: 512 sequential LSTM steps, 1 grid barrier each.
// ---------------------------------------------------------------------------
__global__ __launch_bounds__(NTHR, 2) void enc_mega(
    const float* __restrict__ x, const float* __restrict__ We_ih,
    const float* __restrict__ We_hh, const float* __restrict__ be,
    const float* __restrict__ zero_h, float* out_e, float* c_glob,
    int* barcnt, int* bargen)
{
  __shared__ float w_lds[16 * 1280];
  __shared__ float stage[64 * 258];
  __shared__ float c_lds[256];
  __shared__ float b_lds[16];
  const int tid = threadIdx.x;
  const int j0 = blockIdx.x * 4;

  for (int r = 0; r < 16; ++r) {
    const int grow = (r >> 2) * Hd + j0 + (r & 3);
    const float4* sh = (const float4*)(We_hh + (size_t)grow * Hd);
    for (int kf = tid; kf < 256; kf += NTHR)
      *(float4*)(w_lds + (size_t)r * 1280 + kf * 4) = sh[kf];
    const float4* si = (const float4*)(We_ih + (size_t)grow * Iw);
    for (int kf = tid; kf < 64; kf += NTHR)
      *(float4*)(w_lds + (size_t)r * 1280 + 1024 + kf * 4) = si[kf];
  }
  if (tid < 16) b_lds[tid] = be[(tid >> 2) * Hd + j0 + (tid & 3)];
  if (tid < 256) c_lds[tid] = 0.f;

  for (int t = 0; t < Sx; ++t) {
    const float* hprev = t ? (out_e + (size_t)(t - 1) * NH) : zero_h;
    lstm_tile_step(hprev, x + (size_t)t * NI, out_e + (size_t)t * NH,
                   w_lds, stage, c_lds, b_lds, j0, tid);
    gridbar(barcnt, bargen);
  }
  if (tid < 256) {
    const int n = tid >> 2, jj = tid & 3;
    c_glob[(size_t)n * Hd + j0 + jj] = c_lds[tid];
  }
}

// ---------------------------------------------------------------------------
// pre2[sn][i] = b2[i] + sum_h out_e[sn][h] * W2[i][h]   (grid 2048 x 256)
// ---------------------------------------------------------------------------
__global__ __launch_bounds__(256) void pre2_kernel(
    const float* __restrict__ oute, const float* __restrict__ W2,
    const float* __restrict__ b2, float* __restrict__ pre2)
{
  __shared__ float hl[16 * 1024];
  const int tid = threadIdx.x;
  const int sn0 = blockIdx.x * 16;
  {
    const float4* src = (const float4*)(oute + (size_t)sn0 * Hd);
    float4* dst = (float4*)hl;
    for (int idx = tid; idx < 4096; idx += 256) dst[idx] = src[idx];
  }
  __syncthreads();
  const int i = tid;
  const float4* __restrict__ w = (const float4*)(W2 + (size_t)i * Hd);
  float acc[16];
  #pragma unroll
  for (int ss = 0; ss < 16; ++ss) acc[ss] = 0.0f;
  #pragma unroll 2
  for (int k4 = 0; k4 < 256; ++k4) {
    const float4 wv = w[k4];
    #pragma unroll
    for (int ss = 0; ss < 16; ++ss) {
      const float4 hv = *(const float4*)(hl + ss * 1024 + k4 * 4);
      acc[ss] = fmaf(wv.x, hv.x, acc[ss]); acc[ss] = fmaf(wv.y, hv.y, acc[ss]);
      acc[ss] = fmaf(wv.z, hv.z, acc[ss]); acc[ss] = fmaf(wv.w, hv.w, acc[ss]);
    }
  }
  const float bb = b2[i];
  #pragma unroll
  for (int ss = 0; ss < 16; ++ss)
    pre2[(size_t)(sn0 + ss) * Iw + i] = acc[ss] + bb;
}

// ---------------------------------------------------------------------------
// Decoder megakernel: 128 steps x {q/outlin || -> scores -> softmax+ctx ->
// gemm+gates}, 4 grid barriers per step.
// ---------------------------------------------------------------------------
__global__ __launch_bounds__(NTHR, 2) void dec_mega(
    const float* __restrict__ x, const float* __restrict__ Wd_ih,
    const float* __restrict__ Wd_hh, const float* __restrict__ bd,
    const float* __restrict__ W1, const float* __restrict__ b1,
    const float* __restrict__ w3, const float* __restrict__ b3,
    const float* __restrict__ Wl, const float* __restrict__ bl,
    const float* out_e, const float* __restrict__ pre2,
    const float* __restrict__ c_glob,
    float* q, float* scores, float* ctx, float* h_d, float* out,
    int* barcnt, int* bargen)
{
  __shared__ float w_lds[16 * 1280];
  __shared__ float stage[64 * 258];
  __shared__ float c_lds[256];
  __shared__ float b_lds[16];
  __shared__ float aux[512];
  const int tid = threadIdx.x;
  const int b = blockIdx.x;
  const int j0 = b * 4;

  for (int r = 0; r < 16; ++r) {
    const int grow = (r >> 2) * Hd + j0 + (r & 3);
    const float4* sh = (const float4*)(Wd_hh + (size_t)grow * Hd);
    for (int kf = tid; kf < 256; kf += NTHR)
      *(float4*)(w_lds + (size_t)r * 1280 + kf * 4) = sh[kf];
    const float4* si = (const float4*)(Wd_ih + (size_t)grow * Iw);
    for (int kf = tid; kf < 64; kf += NTHR)
      *(float4*)(w_lds + (size_t)r * 1280 + 1024 + kf * 4) = si[kf];
  }
  if (tid < 16) b_lds[tid] = bd[(tid >> 2) * Hd + j0 + (tid & 3)];
  if (tid < 256) {
    const int n = tid >> 2, jj = tid & 3;
    c_lds[tid] = c_glob[(size_t)n * Hd + j0 + jj];
  }

  const int role = b >> 7;        // 0: q-linear, 1: out-linear
  const int i0 = (b & 127) * 2;

  for (int t = 0; t <= Td; ++t) {
    // ---- Phase QOUT: q(t) = h@W1^T + b1 (blocks 0..127),
    //                  out(t-1) = h@Wl^T + bl (blocks 128..255, t>0) ----
    const float* hin = t ? h_d : (out_e + (size_t)(Sx - 1) * NH);
    {
      const bool active = (role == 0) ? (t < Td) : (t > 0);
      if (active) {
        const float* W = role ? Wl : W1;
        const float* bias = role ? bl : b1;
        float* dst = role ? (out + (size_t)(t - 1) * NI) : q;
        const int nn = tid >> 3, ks = tid & 7;
        float a0 = 0.f, a1 = 0.f;
        const float4* hr = (const float4*)(hin + (size_t)nn * Hd);
        const float4* w0 = (const float4*)(W + (size_t)i0 * Hd);
        const float4* w1 = (const float4*)(W + (size_t)(i0 + 1) * Hd);
        #pragma unroll 4
        for (int kk = 0; kk < 32; ++kk) {
          const int kf4 = kk * 8 + ks;
          const float4 hv = hr[kf4];
          const float4 v0 = w0[kf4], v1 = w1[kf4];
          a0 = fmaf(hv.x, v0.x, a0); a0 = fmaf(hv.y, v0.y, a0);
          a0 = fmaf(hv.z, v0.z, a0); a0 = fmaf(hv.w, v0.w, a0);
          a1 = fmaf(hv.x, v1.x, a1); a1 = fmaf(hv.y, v1.y, a1);
          a1 = fmaf(hv.z, v1.z, a1); a1 = fmaf(hv.w, v1.w, a1);
        }
        __syncthreads();
        stage[(nn * 2 + 0) * 8 + ks] = a0;
        stage[(nn * 2 + 1) * 8 + ks] = a1;
        __syncthreads();
        if (tid < 128) {
          const int n = tid >> 1, ii = tid & 1;
          const float* p = stage + (n * 2 + ii) * 8;
          const float s = ((p[0] + p[1]) + (p[2] + p[3])) + ((p[4] + p[5]) + (p[6] + p[7]));
          dst[(size_t)n * Iw + i0 + ii] = s + bias[i0 + ii];
        }
      }
    }
    if (t == Td) break;
    gridbar(barcnt, bargen);

    // ---- Phase SC: scores[n][s] for s in {2b, 2b+1} ----
    {
      const int sn = tid >> 2, isl = tid & 3;
      const int s = 2 * b + (sn >> 6);
      const int n = sn & 63;
      const float* pr = pre2 + ((size_t)s * Nb + n) * Iw + isl * 64;
      const float* qr = q + (size_t)n * Iw + isl * 64;
      const float* wr = w3 + isl * 64;
      float a = 0.f;
      #pragma unroll 4
      for (int m = 0; m < 16; ++m) {
        const float4 p = *(const float4*)(pr + m * 4);
        const float4 qv = *(const float4*)(qr + m * 4);
        const float4 wv = *(const float4*)(wr + m * 4);
        a += tanhf_(p.x + qv.x) * wv.x + tanhf_(p.y + qv.y) * wv.y
           + tanhf_(p.z + qv.z) * wv.z + tanhf_(p.w + qv.w) * wv.w;
      }
      __syncthreads();
      aux[tid] = a;
      __syncthreads();
      if (tid < 128) {
        const int s2 = 2 * b + (tid >> 6);
        const int n2 = tid & 63;
        const float* p = aux + tid * 4;
        scores[(size_t)n2 * Sx + s2] = (p[0] + p[1]) + (p[2] + p[3]) + b3[0];
      }
    }
    gridbar(barcnt, bargen);

    // ---- Phase CTX: local softmax + ctx[n][hq*256..] ----
    {
      const int n = b >> 2, hq = b & 3;
      const float sv = scores[(size_t)n * Sx + tid];
      __syncthreads();
      aux[tid] = sv;
      __syncthreads();
      for (int w = 256; w >= 1; w >>= 1) {
        if (tid < w) aux[tid] = fmaxf(aux[tid], aux[tid + w]);
        __syncthreads();
      }
      const float mx = aux[0];
      __syncthreads();
      const float ev = __expf(sv - mx);
      aux[tid] = ev;
      __syncthreads();
      for (int w = 256; w >= 1; w >>= 1) {
        if (tid < w) aux[tid] += aux[tid + w];
        __syncthreads();
      }
      const float inv = 1.0f / aux[0];
      __syncthreads();
      stage[tid] = ev * inv;        // alpha[s]
      __syncthreads();
      const int h4 = tid & 63, ss = tid >> 6;
      const float* base = out_e + (size_t)n * Hd + hq * 256 + h4 * 4;
      float A0 = 0.f, A1 = 0.f, A2 = 0.f, A3 = 0.f;
      for (int si = ss * 64; si < ss * 64 + 64; ++si) {
        const float al = stage[si];
        const float4 v = *(const float4*)(base + (size_t)si * NH);
        A0 = fmaf(al, v.x, A0); A1 = fmaf(al, v.y, A1);
        A2 = fmaf(al, v.z, A2); A3 = fmaf(al, v.w, A3);
      }
      stage[512 + (h4 * 4 + 0) * 8 + ss] = A0;
      stage[512 + (h4 * 4 + 1) * 8 + ss] = A1;
      stage[512 + (h4 * 4 + 2) * 8 + ss] = A2;
      stage[512 + (h4 * 4 + 3) * 8 + ss] = A3;
      __syncthreads();
      if (tid < 256) {
        const float* p = stage + 512 + (size_t)tid * 8;
        const float v = ((p[0] + p[1]) + (p[2] + p[3])) + ((p[4] + p[5]) + (p[6] + p[7]));
        ctx[(size_t)n * Hd + hq * 256 + tid] = v;
      }
    }
    gridbar(barcnt, bargen);

    // ---- Phase GEMM+GATES: h_d(t), c update ----
    {
      const float* inp = t ? (out + (size_t)(t - 1) * NI) : (x + (size_t)(Sx - 1) * NI);
      lstm_tile_step(ctx, inp, h_d, w_lds, stage, c_lds, b_lds, j0, tid);
    }
    gridbar(barcnt, bargen);
  }
}

// ---------------------------------------------------------------------------
extern "C" void kernel_launch(void* const* d_in, const int* in_sizes, int n_in,
                              void* d_out, int out_size, void* d_ws, size_t ws_size,
                              hipStream_t stream) {
  (void)in_sizes; (void)n_in; (void)out_size; (void)ws_size;
  const float* x     = (const float*)d_in[0];
  // d_in[1] = target_len (constant 128) — ignored
  const float* We_ih = (const float*)d_in[2];
  const float* We_hh = (const float*)d_in[3];
  const float* be    = (const float*)d_in[4];
  const float* Wd_ih = (const float*)d_in[5];
  const float* Wd_hh = (const float*)d_in[6];
  const float* bd    = (const float*)d_in[7];
  const float* W1    = (const float*)d_in[8];
  const float* b1    = (const float*)d_in[9];
  const float* W2    = (const float*)d_in[10];
  const float* b2    = (const float*)d_in[11];
  const float* w3    = (const float*)d_in[12];
  const float* b3    = (const float*)d_in[13];
  const float* Wl    = (const float*)d_in[14];
  const float* bl    = (const float*)d_in[15];
  float* out = (float*)d_out;

  // Workspace layout (floats), ~161 MB
  float* ws     = (float*)d_ws;
  float* out_e  = ws;                                  // S*N*H  (128 MB)
  float* pre2   = out_e + (size_t)Sx * NH;             // S*N*I  (32 MB)
  float* zero_h = pre2 + (size_t)Sx * NI;              // N*H
  float* c_glob = zero_h + NH;                         // N*H
  float* qb     = c_glob + NH;                         // N*I
  float* scb    = qb + NI;                             // N*S
  float* ctxb   = scb + Nb * Sx;                       // N*H
  float* h_d    = ctxb + NH;                           // N*H
  int*   bar    = (int*)(h_d + NH);                    // cnt @0, gen @64

  hipMemsetAsync(zero_h, 0, (size_t)NH * sizeof(float), stream);
  hipMemsetAsync(bar, 0, 128 * sizeof(int), stream);

  int* barcnt = bar;
  int* bargen = bar + 64;

  {
    void* args[] = {(void*)&x, (void*)&We_ih, (void*)&We_hh, (void*)&be,
                    (void*)&zero_h, (void*)&out_e, (void*)&c_glob,
                    (void*)&barcnt, (void*)&bargen};
    hipLaunchCooperativeKernel(reinterpret_cast<void*>(enc_mega),
                               dim3(NBLK), dim3(NTHR), args, 0, stream);
  }

  pre2_kernel<<<2048, 256, 0, stream>>>(out_e, W2, b2, pre2);

  {
    void* args[] = {(void*)&x, (void*)&Wd_ih, (void*)&Wd_hh, (void*)&bd,
                    (void*)&W1, (void*)&b1, (void*)&w3, (void*)&b3,
                    (void*)&Wl, (void*)&bl, (void*)&out_e, (void*)&pre2,
                    (void*)&c_glob, (void*)&qb, (void*)&scb, (void*)&ctxb,
                    (void*)&h_d, (void*)&out, (void*)&barcnt, (void*)&bargen};
    hipLaunchCooperativeKernel(reinterpret_cast<void*>(dec_mega),
                               dim3(NBLK), dim3(NTHR), args, 0, stream);
  }
}

// Round 5
// 38624.927 us; speedup vs baseline: 3.1292x; 1.0191x over previous
//
#include <hip/hip_runtime.h>

typedef unsigned short ushort_t;
typedef unsigned int uint_t;

// Problem constants (match reference)
constexpr int Sx = 512;   // source sequence length
constexpr int Nb = 64;    // batch
constexpr int Iw = 256;   // input/feature dim
constexpr int Hd = 1024;  // hidden dim
constexpr int Td = 128;   // target length
constexpr int NH = Nb * Hd;   // 65536
constexpr int NI = Nb * Iw;   // 16384
constexpr int NBLK = 256;
constexpr int NTHR = 512;
constexpr int WROW = 1284;    // w_lds row stride (floats): 1280 + 4 pad
constexpr int SROW = 260;     // stage row stride (floats): 256 + 4 pad

#define DEVFN __device__ __forceinline__

DEVFN float sigmoidf_(float x) { return 1.0f / (1.0f + __expf(-x)); }
DEVFN float tanhf_(float x) {
  const float t = __expf(-2.0f * fabsf(x));
  const float r = (1.0f - t) / (1.0f + t);
  return copysignf(r, x);
}
// bf16 helpers (bit-exact read; RTNE write)
DEVFN float bflo(uint_t u) { return __uint_as_float(u << 16); }
DEVFN float bfhi(uint_t u) { return __uint_as_float(u & 0xFFFF0000u); }
DEVFN ushort_t f2b(float f) {
  uint_t u = __float_as_uint(f);
  u = (u + 0x7FFFu + ((u >> 16) & 1u)) >> 16;
  return (ushort_t)u;
}

// Device-scope grid barrier (generation counter; cnt/gen zeroed by host
// memset each launch; agent-scope fences for cross-XCD visibility).
DEVFN void gridbar(int* cnt, int* gen) {
  __syncthreads();
  if (threadIdx.x == 0) {
    __threadfence();
    int g = __hip_atomic_load(gen, __ATOMIC_RELAXED, __HIP_MEMORY_SCOPE_AGENT);
    int a = __hip_atomic_fetch_add(cnt, 1, __ATOMIC_ACQ_REL, __HIP_MEMORY_SCOPE_AGENT);
    if (a == NBLK - 1) {
      __hip_atomic_store(cnt, 0, __ATOMIC_RELAXED, __HIP_MEMORY_SCOPE_AGENT);
      __hip_atomic_fetch_add(gen, 1, __ATOMIC_RELEASE, __HIP_MEMORY_SCOPE_AGENT);
    } else {
      while (__hip_atomic_load(gen, __ATOMIC_RELAXED, __HIP_MEMORY_SCOPE_AGENT) == g)
        __builtin_amdgcn_s_sleep(2);
    }
    __threadfence();
  }
  __syncthreads();
}

// ---------------------------------------------------------------------------
// One LSTM step for this block's 4 j-columns (16 weight rows resident in
// w_lds[16][WROW]: quads 0..255 = W_hh, 256..319 = W_ih).
// Thread tile: 8n x 8r x 32-ksplit.  tid = ks*16 + rp*8 + np:
//   np in 0..7 -> n = 8*i + np (i=0..7, stride-8 so np enters the bank quad)
//   rp in 0..1 -> r = rp*8 + j (j=0..7)
//   ks in 0..31 -> k-quads kq = kk*32 + ks (kk=0..1) per 256-k chunk.
// Per kq: 8 w-b128 (4-distinct broadcast, ~free) + 8 h-b128 (32 distinct,
// bank-quad (np+kq)&7 even spread = volume floor) + 256 FMA.
// Reduce: shfl_xor over ks&3 (lane bits 4,5), then LDS p[1024][9] over waves.
// ---------------------------------------------------------------------------
DEVFN void lstm_tile_step(
    const float* hsrc,               // N x Hd  (h_prev or ctx)
    const float* xsrc,               // N x Iw  (x_t or inp)
    float* hdst,                     // N x Hd
    ushort_t* hdst_b16,              // N x Hd bf16 copy (or null)
    const float* w_lds, float* stage, float* c_lds, const float* b_lds,
    int j0, int tid)
{
  const int np = tid & 7;
  const int rp = (tid >> 3) & 1;
  const int ks = tid >> 4;          // 0..31

  float acc[8][8];
  #pragma unroll
  for (int i = 0; i < 8; ++i)
    #pragma unroll
    for (int j = 0; j < 8; ++j) acc[i][j] = 0.f;

  for (int c = 0; c < 5; ++c) {
    __syncthreads();
    const float* src = (c < 4) ? (hsrc + c * 256) : xsrc;
    const int sstr = (c < 4) ? Hd : Iw;
    for (int idx = tid; idx < 4096; idx += NTHR) {
      const int kq = idx & 63, nn = idx >> 6;
      *(float4*)(stage + nn * SROW + kq * 4) =
          *(const float4*)(src + (size_t)nn * sstr + kq * 4);
    }
    __syncthreads();
    #pragma unroll
    for (int kk = 0; kk < 2; ++kk) {
      const int kq = kk * 32 + ks;               // chunk-local quad 0..63
      const int wq = c * 64 + kq;                // global quad 0..319
      float4 wv[8];
      #pragma unroll
      for (int j = 0; j < 8; ++j)
        wv[j] = *(const float4*)(w_lds + (size_t)(rp * 8 + j) * WROW + wq * 4);
      #pragma unroll
      for (int i = 0; i < 8; ++i) {
        const float4 hq = *(const float4*)(stage + (size_t)(i * 8 + np) * SROW + kq * 4);
        #pragma unroll
        for (int j = 0; j < 8; ++j) {
          acc[i][j] = fmaf(hq.x, wv[j].x, acc[i][j]);
          acc[i][j] = fmaf(hq.y, wv[j].y, acc[i][j]);
          acc[i][j] = fmaf(hq.z, wv[j].z, acc[i][j]);
          acc[i][j] = fmaf(hq.w, wv[j].w, acc[i][j]);
        }
      }
    }
  }

  // in-wave reduce over ks low bits (lane bits 4,5)
  #pragma unroll
  for (int i = 0; i < 8; ++i)
    #pragma unroll
    for (int j = 0; j < 8; ++j) {
      float v = acc[i][j];
      v += __shfl_xor(v, 16);
      v += __shfl_xor(v, 32);
      acc[i][j] = v;
    }
  __syncthreads();            // stage reusable as partial buffer p[1024][9]
  const int wv8 = tid >> 6;   // wave 0..7
  if ((tid & 48) == 0) {
    #pragma unroll
    for (int i = 0; i < 8; ++i)
      #pragma unroll
      for (int j = 0; j < 8; ++j) {
        const int r = rp * 8 + j, n = i * 8 + np;
        stage[(size_t)(r * 64 + n) * 9 + wv8] = acc[i][j];
      }
  }
  __syncthreads();
  if (tid < 256) {
    const int n = tid >> 2, jj = tid & 3;
    float v[4];
    #pragma unroll
    for (int g = 0; g < 4; ++g) {
      const float* p = stage + (size_t)((g * 4 + jj) * 64 + n) * 9;
      float s = ((p[0] + p[1]) + (p[2] + p[3])) + ((p[4] + p[5]) + (p[6] + p[7]));
      v[g] = b_lds[g * 4 + jj] + s;
    }
    const float ig = sigmoidf_(v[0]);
    const float fg = sigmoidf_(v[1]);
    const float gg = tanhf_(v[2]);
    const float og = sigmoidf_(v[3]);
    const float cn = fg * c_lds[tid] + ig * gg;
    c_lds[tid] = cn;
    const float hv = og * tanhf_(cn);
    hdst[(size_t)n * Hd + j0 + jj] = hv;
    if (hdst_b16) hdst_b16[(size_t)n * Hd + j0 + jj] = f2b(hv);
  }
}

DEVFN void load_weights(const float* Whh, const float* Wih, const float* bias,
                        float* w_lds, float* b_lds, int j0, int tid) {
  for (int r = 0; r < 16; ++r) {
    const int grow = (r >> 2) * Hd + j0 + (r & 3);
    const float4* sh = (const float4*)(Whh + (size_t)grow * Hd);
    for (int kf = tid; kf < 256; kf += NTHR)
      *(float4*)(w_lds + (size_t)r * WROW + kf * 4) = sh[kf];
    const float4* si = (const float4*)(Wih + (size_t)grow * Iw);
    for (int kf = tid; kf < 64; kf += NTHR)
      *(float4*)(w_lds + (size_t)r * WROW + 1024 + kf * 4) = si[kf];
  }
  if (tid < 16) b_lds[tid] = bias[(tid >> 2) * Hd + j0 + (tid & 3)];
}

// ---------------------------------------------------------------------------
// Encoder megakernel: 512 sequential LSTM steps, 1 grid barrier each.
// fp32 h ping-pong (hbuf[2]) for the recurrence; bf16 history to out_eb.
// ---------------------------------------------------------------------------
__global__ __launch_bounds__(NTHR, 2) void enc_mega(
    const float* __restrict__ x, const float* __restrict__ We_ih,
    const float* __restrict__ We_hh, const float* __restrict__ be,
    float* hbuf0, float* hbuf1, ushort_t* out_eb, float* c_glob,
    int* barcnt, int* bargen)
{
  __shared__ float w_lds[16 * WROW];
  __shared__ float stage[64 * SROW];
  __shared__ float c_lds[256];
  __shared__ float b_lds[16];
  const int tid = threadIdx.x;
  const int j0 = blockIdx.x * 4;

  load_weights(We_hh, We_ih, be, w_lds, b_lds, j0, tid);
  if (tid < 256) c_lds[tid] = 0.f;

  for (int t = 0; t < Sx; ++t) {
    float* hin = (t & 1) ? hbuf1 : hbuf0;
    float* hout = (t & 1) ? hbuf0 : hbuf1;
    lstm_tile_step(hin, x + (size_t)t * NI, hout, out_eb + (size_t)t * NH,
                   w_lds, stage, c_lds, b_lds, j0, tid);
    gridbar(barcnt, bargen);
  }
  if (tid < 256) {
    const int n = tid >> 2, jj = tid & 3;
    c_glob[(size_t)n * Hd + j0 + jj] = c_lds[tid];
  }
}

// ---------------------------------------------------------------------------
// pre2b[sn][i] = bf16( b2[i] + sum_h out_eb[sn][h] * W2[i][h] )
// grid 2048 x 256; block: 16 sn rows (bf16 -> fp32 staged in LDS).
// ---------------------------------------------------------------------------
__global__ __launch_bounds__(256) void pre2_kernel(
    const ushort_t* __restrict__ outeb, const float* __restrict__ W2,
    const float* __restrict__ b2, ushort_t* __restrict__ pre2b)
{
  __shared__ float hl[16 * 1024];
  const int tid = threadIdx.x;
  const int sn0 = blockIdx.x * 16;
  for (int idx = tid; idx < 2048; idx += 256) {
    const uint4 u = *(const uint4*)(outeb + (size_t)sn0 * Hd + idx * 8);
    float4 a = {bflo(u.x), bfhi(u.x), bflo(u.y), bfhi(u.y)};
    float4 b = {bflo(u.z), bfhi(u.z), bflo(u.w), bfhi(u.w)};
    *(float4*)(hl + idx * 8) = a;
    *(float4*)(hl + idx * 8 + 4) = b;
  }
  __syncthreads();
  const int i = tid;
  const float4* __restrict__ w = (const float4*)(W2 + (size_t)i * Hd);
  float acc[16];
  #pragma unroll
  for (int ss = 0; ss < 16; ++ss) acc[ss] = 0.0f;
  #pragma unroll 2
  for (int k4 = 0; k4 < 256; ++k4) {
    const float4 wv = w[k4];
    #pragma unroll
    for (int ss = 0; ss < 16; ++ss) {
      const float4 hv = *(const float4*)(hl + ss * 1024 + k4 * 4);
      acc[ss] = fmaf(wv.x, hv.x, acc[ss]); acc[ss] = fmaf(wv.y, hv.y, acc[ss]);
      acc[ss] = fmaf(wv.z, hv.z, acc[ss]); acc[ss] = fmaf(wv.w, hv.w, acc[ss]);
    }
  }
  const float bb = b2[i];
  #pragma unroll
  for (int ss = 0; ss < 16; ++ss)
    pre2b[(size_t)(sn0 + ss) * Iw + i] = f2b(acc[ss] + bb);
}

// ---------------------------------------------------------------------------
// Decoder megakernel: 128 steps x {q/outlin -> scores -> softmax+ctx ->
// lstm+gates}, 4 grid barriers per step.
// ---------------------------------------------------------------------------
__global__ __launch_bounds__(NTHR, 2) void dec_mega(
    const float* __restrict__ x, const float* __restrict__ Wd_ih,
    const float* __restrict__ Wd_hh, const float* __restrict__ bd,
    const float* __restrict__ W1, const float* __restrict__ b1,
    const float* __restrict__ w3, const float* __restrict__ b3,
    const float* __restrict__ Wl, const float* __restrict__ bl,
    const float* h_e, const ushort_t* out_eb, const ushort_t* __restrict__ pre2b,
    const float* __restrict__ c_glob,
    float* q, float* scores, float* ctx, float* h_d, float* out,
    int* barcnt, int* bargen)
{
  __shared__ float w_lds[16 * WROW];
  __shared__ float stage[64 * SROW];
  __shared__ float c_lds[256];
  __shared__ float b_lds[16];
  __shared__ float aux[512];
  const int tid = threadIdx.x;
  const int b = blockIdx.x;
  const int j0 = b * 4;

  load_weights(Wd_hh, Wd_ih, bd, w_lds, b_lds, j0, tid);
  if (tid < 256) {
    const int n = tid >> 2, jj = tid & 3;
    c_lds[tid] = c_glob[(size_t)n * Hd + j0 + jj];
  }

  const int role = b >> 7;        // 0: q-linear, 1: out-linear
  const int i0 = (b & 127) * 2;

  for (int t = 0; t <= Td; ++t) {
    // ---- Phase QOUT: q(t) (blocks 0..127) / out(t-1) (blocks 128..255) ----
    const float* hin = t ? h_d : h_e;
    {
      const bool active = (role == 0) ? (t < Td) : (t > 0);
      if (active) {
        const float* W = role ? Wl : W1;
        const float* bias = role ? bl : b1;
        float* dst = role ? (out + (size_t)(t - 1) * NI) : q;
        const int nn = tid >> 3, ksl = tid & 7;
        float a0 = 0.f, a1 = 0.f;
        const float4* hr = (const float4*)(hin + (size_t)nn * Hd);
        const float4* w0 = (const float4*)(W + (size_t)i0 * Hd);
        const float4* w1 = (const float4*)(W + (size_t)(i0 + 1) * Hd);
        #pragma unroll 4
        for (int kk = 0; kk < 32; ++kk) {
          const int kf4 = kk * 8 + ksl;
          const float4 hv = hr[kf4];
          const float4 v0 = w0[kf4], v1 = w1[kf4];
          a0 = fmaf(hv.x, v0.x, a0); a0 = fmaf(hv.y, v0.y, a0);
          a0 = fmaf(hv.z, v0.z, a0); a0 = fmaf(hv.w, v0.w, a0);
          a1 = fmaf(hv.x, v1.x, a1); a1 = fmaf(hv.y, v1.y, a1);
          a1 = fmaf(hv.z, v1.z, a1); a1 = fmaf(hv.w, v1.w, a1);
        }
        __syncthreads();
        stage[(nn * 2 + 0) * 8 + ksl] = a0;
        stage[(nn * 2 + 1) * 8 + ksl] = a1;
        __syncthreads();
        if (tid < 128) {
          const int n = tid >> 1, ii = tid & 1;
          const float* p = stage + (n * 2 + ii) * 8;
          const float s = ((p[0] + p[1]) + (p[2] + p[3])) + ((p[4] + p[5]) + (p[6] + p[7]));
          dst[(size_t)n * Iw + i0 + ii] = s + bias[i0 + ii];
        }
      }
    }
    if (t == Td) break;
    gridbar(barcnt, bargen);

    // ---- Phase SC: scores[n][s] for s in {2b, 2b+1}; pre2 read as bf16 ----
    {
      const int sn = tid >> 2, isl = tid & 3;
      const int s = 2 * b + (sn >> 6);
      const int n = sn & 63;
      const ushort_t* pr = pre2b + ((size_t)s * Nb + n) * Iw + isl * 64;
      const float* qr = q + (size_t)n * Iw + isl * 64;
      const float* wr = w3 + isl * 64;
      float a = 0.f;
      #pragma unroll 2
      for (int m = 0; m < 8; ++m) {
        const uint4 u = *(const uint4*)(pr + m * 8);
        const float4 q0 = *(const float4*)(qr + m * 8);
        const float4 q1 = *(const float4*)(qr + m * 8 + 4);
        const float4 w0 = *(const float4*)(wr + m * 8);
        const float4 w1 = *(const float4*)(wr + m * 8 + 4);
        a += tanhf_(bflo(u.x) + q0.x) * w0.x + tanhf_(bfhi(u.x) + q0.y) * w0.y
           + tanhf_(bflo(u.y) + q0.z) * w0.z + tanhf_(bfhi(u.y) + q0.w) * w0.w;
        a += tanhf_(bflo(u.z) + q1.x) * w1.x + tanhf_(bfhi(u.z) + q1.y) * w1.y
           + tanhf_(bflo(u.w) + q1.z) * w1.z + tanhf_(bfhi(u.w) + q1.w) * w1.w;
      }
      __syncthreads();
      aux[tid] = a;
      __syncthreads();
      if (tid < 128) {
        const int s2 = 2 * b + (tid >> 6);
        const int n2 = tid & 63;
        const float* p = aux + tid * 4;
        scores[(size_t)n2 * Sx + s2] = (p[0] + p[1]) + (p[2] + p[3]) + b3[0];
      }
    }
    gridbar(barcnt, bargen);

    // ---- Phase CTX: softmax over s + ctx[n][hq*256..] from bf16 out_eb ----
    {
      const int n = b >> 2, hq = b & 3;
      const float sv = scores[(size_t)n * Sx + tid];
      aux[tid] = sv;
      __syncthreads();
      for (int w = 256; w >= 1; w >>= 1) {
        if (tid < w) aux[tid] = fmaxf(aux[tid], aux[tid + w]);
        __syncthreads();
      }
      const float mx = aux[0];
      __syncthreads();
      const float ev = __expf(sv - mx);
      aux[tid] = ev;
      __syncthreads();
      for (int w = 256; w >= 1; w >>= 1) {
        if (tid < w) aux[tid] += aux[tid + w];
        __syncthreads();
      }
      const float inv = 1.0f / aux[0];
      __syncthreads();
      stage[tid] = ev * inv;        // alpha[s]
      __syncthreads();
      const int h8 = tid & 31, ss = tid >> 5;   // 16 s-groups x 32 h-octets
      const ushort_t* bp = out_eb + (size_t)n * Hd + hq * 256 + h8 * 8;
      float A[8];
      #pragma unroll
      for (int e = 0; e < 8; ++e) A[e] = 0.f;
      #pragma unroll 4
      for (int si = ss * 32; si < ss * 32 + 32; ++si) {
        const float al = stage[si];
        const uint4 u = *(const uint4*)(bp + (size_t)si * NH);
        A[0] = fmaf(al, bflo(u.x), A[0]); A[1] = fmaf(al, bfhi(u.x), A[1]);
        A[2] = fmaf(al, bflo(u.y), A[2]); A[3] = fmaf(al, bfhi(u.y), A[3]);
        A[4] = fmaf(al, bflo(u.z), A[4]); A[5] = fmaf(al, bfhi(u.z), A[5]);
        A[6] = fmaf(al, bflo(u.w), A[6]); A[7] = fmaf(al, bfhi(u.w), A[7]);
      }
      float4 lo = {A[0], A[1], A[2], A[3]};
      float4 hi = {A[4], A[5], A[6], A[7]};
      *(float4*)(stage + 1024 + ss * 264 + h8 * 8) = lo;
      *(float4*)(stage + 1024 + ss * 264 + h8 * 8 + 4) = hi;
      __syncthreads();
      if (tid < 256) {
        float s = 0.f;
        #pragma unroll
        for (int sg = 0; sg < 16; ++sg) s += stage[1024 + sg * 264 + tid];
        ctx[(size_t)n * Hd + hq * 256 + tid] = s;
      }
    }
    gridbar(barcnt, bargen);

    // ---- Phase LSTM: h_d(t), c update (hidden = ctx, input = out[t-1]) ----
    {
      const float* inp = t ? (out + (size_t)(t - 1) * NI) : (x + (size_t)(Sx - 1) * NI);
      lstm_tile_step(ctx, inp, h_d, nullptr, w_lds, stage, c_lds, b_lds, j0, tid);
    }
    gridbar(barcnt, bargen);
  }
}

// ---------------------------------------------------------------------------
extern "C" void kernel_launch(void* const* d_in, const int* in_sizes, int n_in,
                              void* d_out, int out_size, void* d_ws, size_t ws_size,
                              hipStream_t stream) {
  (void)in_sizes; (void)n_in; (void)out_size; (void)ws_size;
  const float* x     = (const float*)d_in[0];
  // d_in[1] = target_len (constant 128) — ignored
  const float* We_ih = (const float*)d_in[2];
  const float* We_hh = (const float*)d_in[3];
  const float* be    = (const float*)d_in[4];
  const float* Wd_ih = (const float*)d_in[5];
  const float* Wd_hh = (const float*)d_in[6];
  const float* bd    = (const float*)d_in[7];
  const float* W1    = (const float*)d_in[8];
  const float* b1    = (const float*)d_in[9];
  const float* W2    = (const float*)d_in[10];
  const float* b2    = (const float*)d_in[11];
  const float* w3    = (const float*)d_in[12];
  const float* b3    = (const float*)d_in[13];
  const float* Wl    = (const float*)d_in[14];
  const float* bl    = (const float*)d_in[15];
  float* out = (float*)d_out;

  // Workspace layout: fp32 region then bf16 region (~82 MB total)
  float* ws     = (float*)d_ws;
  float* hbuf0  = ws;                                  // N*H
  float* hbuf1  = hbuf0 + NH;                          // N*H
  float* c_glob = hbuf1 + NH;                          // N*H
  float* qb     = c_glob + NH;                         // N*I
  float* scb    = qb + NI;                             // N*S
  float* ctxb   = scb + Nb * Sx;                       // N*H
  float* h_d    = ctxb + NH;                           // N*H
  int*   bar    = (int*)(h_d + NH);                    // 128 ints
  ushort_t* out_eb = (ushort_t*)(bar + 128);           // S*N*H bf16 (64 MB)
  ushort_t* pre2b  = out_eb + (size_t)Sx * NH;         // S*N*I bf16 (16 MB)

  hipMemsetAsync(hbuf0, 0, (size_t)NH * sizeof(float), stream);
  hipMemsetAsync(bar, 0, 128 * sizeof(int), stream);

  int* barcnt = bar;
  int* bargen = bar + 64;

  {
    void* args[] = {(void*)&x, (void*)&We_ih, (void*)&We_hh, (void*)&be,
                    (void*)&hbuf0, (void*)&hbuf1, (void*)&out_eb, (void*)&c_glob,
                    (void*)&barcnt, (void*)&bargen};
    hipLaunchCooperativeKernel(reinterpret_cast<void*>(enc_mega),
                               dim3(NBLK), dim3(NTHR), args, 0, stream);
  }

  pre2_kernel<<<2048, 256, 0, stream>>>(out_eb, W2, b2, pre2b);

  {
    // final encoder h: after 512 steps, last write went to hbuf[(511+1)&1] = hbuf0
    float* h_e = hbuf0;
    void* args[] = {(void*)&x, (void*)&Wd_ih, (void*)&Wd_hh, (void*)&bd,
                    (void*)&W1, (void*)&b1, (void*)&w3, (void*)&b3,
                    (void*)&Wl, (void*)&bl, (void*)&h_e, (void*)&out_eb,
                    (void*)&pre2b, (void*)&c_glob, (void*)&qb, (void*)&scb,
                    (void*)&ctxb, (void*)&h_d, (void*)&out,
                    (void*)&barcnt, (void*)&bargen};
    hipLaunchCooperativeKernel(reinterpret_cast<void*>(dec_mega),
                               dim3(NBLK), dim3(NTHR), args, 0, stream);
  }
}